// Round 16
// baseline (53088.928 us; speedup 1.0000x reference)
//
#include <hip/hip_runtime.h>

#define HH    100
#define G4    400
#define LSEQ  168
#define STEPS 48
#define NTICK 8066     // per-batch ticks: L0 at tick t (t<8064), L1 at tick t-1
#define SHP   112      // padded h stride (zeros beyond 100)
#define NX    176      // extra rows: Wih1 368..399 (32) + Whh1 256..399 (144)
#define NX4   4400     // float4 units in the extra-row panel
#define NX4P  4416     // padded (waves 13..15 read up to idx 4415)

__device__ __forceinline__ float sigmoidf_(float x) {
    return 1.0f / (1.0f + __expf(-x));
}
__device__ __forceinline__ float tanhf_(float x) {
    return 1.0f - 2.0f / (__expf(2.0f * x) + 1.0f);
}

// ---- DPP broadcast-FMA blocks (single-batch) ------------------------------
// v_fmac_f32_dpp row_newbcast: broadcast within 16-lane rows fused into the
// fmac. Round-16 change: ALL 25 weight chunks live in registers (wv[100]) —
// the wlds LDS tail-chunks are gone (32 KB/window of barrier-phase LDS burst
// removed; the LDS pipe is per-CU and was serializing the window head).
// Variadic indirection layer per round-9 lesson. Blocks chain through "+v"
// accumulators -> indivisible (rounds 1-4 spill cascade prevention).

#define DC1(...)   DC1_I(__VA_ARGS__)
#define DC10(...)  DC10_I(__VA_ARGS__)
#define DC1X(...)  DC1X_I(__VA_ARGS__)
#define DC1X0(...) DC1X0_I(__VA_ARGS__)

// One 4-k chunk, 1 batch: 4 DPP-fmacs, chains a0/a0b (round-13 proven).
#define DC1_I(N_, hx,hy,hz,hw, w0_,w1_,w2_,w3_)                                \
    asm("v_fmac_f32_dpp %0, %2, %6 row_newbcast:" #N_ " row_mask:0xf bank_mask:0xf\n\t" \
        "v_fmac_f32_dpp %1, %3, %7 row_newbcast:" #N_ " row_mask:0xf bank_mask:0xf\n\t" \
        "v_fmac_f32_dpp %0, %4, %8 row_newbcast:" #N_ " row_mask:0xf bank_mask:0xf\n\t" \
        "v_fmac_f32_dpp %1, %5, %9 row_newbcast:" #N_ " row_mask:0xf bank_mask:0xf\n\t" \
        : "+v"(a0), "+v"(a0b)                                                  \
        : "v"(hx), "v"(hy), "v"(hz), "v"(hw),                                  \
          "v"(w0_), "v"(w1_), "v"(w2_), "v"(w3_))

// First block after the h load: s_nop guards the load->DPP-read window.
#define DC10_I(N_, hx,hy,hz,hw, w0_,w1_,w2_,w3_)                               \
    asm("s_nop 1\n\t"                                                          \
        "v_fmac_f32_dpp %0, %2, %6 row_newbcast:" #N_ " row_mask:0xf bank_mask:0xf\n\t" \
        "v_fmac_f32_dpp %1, %3, %7 row_newbcast:" #N_ " row_mask:0xf bank_mask:0xf\n\t" \
        "v_fmac_f32_dpp %0, %4, %8 row_newbcast:" #N_ " row_mask:0xf bank_mask:0xf\n\t" \
        "v_fmac_f32_dpp %1, %5, %9 row_newbcast:" #N_ " row_mask:0xf bank_mask:0xf\n\t" \
        : "+v"(a0), "+v"(a0b)                                                  \
        : "v"(hx), "v"(hy), "v"(hz), "v"(hw),                                  \
          "v"(w0_), "v"(w1_), "v"(w2_), "v"(w3_))

// Heavy-wave variant: + extras stream. 8 fmacs, 4 chains, distance 4.
#define DC1X_I(N_, hx,hy,hz,hw, w0_,w1_,w2_,w3_, x0_,x1_,x2_,x3_)              \
    asm("v_fmac_f32_dpp %0, %4, %8 row_newbcast:" #N_ " row_mask:0xf bank_mask:0xf\n\t"  \
        "v_fmac_f32_dpp %2, %4, %12 row_newbcast:" #N_ " row_mask:0xf bank_mask:0xf\n\t" \
        "v_fmac_f32_dpp %1, %5, %9 row_newbcast:" #N_ " row_mask:0xf bank_mask:0xf\n\t"  \
        "v_fmac_f32_dpp %3, %5, %13 row_newbcast:" #N_ " row_mask:0xf bank_mask:0xf\n\t" \
        "v_fmac_f32_dpp %0, %6, %10 row_newbcast:" #N_ " row_mask:0xf bank_mask:0xf\n\t" \
        "v_fmac_f32_dpp %2, %6, %14 row_newbcast:" #N_ " row_mask:0xf bank_mask:0xf\n\t" \
        "v_fmac_f32_dpp %1, %7, %11 row_newbcast:" #N_ " row_mask:0xf bank_mask:0xf\n\t" \
        "v_fmac_f32_dpp %3, %7, %15 row_newbcast:" #N_ " row_mask:0xf bank_mask:0xf\n\t" \
        : "+v"(a0), "+v"(a0b), "+v"(xa0), "+v"(xa0b)                           \
        : "v"(hx), "v"(hy), "v"(hz), "v"(hw),                                  \
          "v"(w0_), "v"(w1_), "v"(w2_), "v"(w3_),                              \
          "v"(x0_), "v"(x1_), "v"(x2_), "v"(x3_))

#define DC1X0_I(N_, hx,hy,hz,hw, w0_,w1_,w2_,w3_, x0_,x1_,x2_,x3_)             \
    asm("s_nop 1\n\t"                                                          \
        "v_fmac_f32_dpp %0, %4, %8 row_newbcast:" #N_ " row_mask:0xf bank_mask:0xf\n\t"  \
        "v_fmac_f32_dpp %2, %4, %12 row_newbcast:" #N_ " row_mask:0xf bank_mask:0xf\n\t" \
        "v_fmac_f32_dpp %1, %5, %9 row_newbcast:" #N_ " row_mask:0xf bank_mask:0xf\n\t"  \
        "v_fmac_f32_dpp %3, %5, %13 row_newbcast:" #N_ " row_mask:0xf bank_mask:0xf\n\t" \
        "v_fmac_f32_dpp %0, %6, %10 row_newbcast:" #N_ " row_mask:0xf bank_mask:0xf\n\t" \
        "v_fmac_f32_dpp %2, %6, %14 row_newbcast:" #N_ " row_mask:0xf bank_mask:0xf\n\t" \
        "v_fmac_f32_dpp %1, %7, %11 row_newbcast:" #N_ " row_mask:0xf bank_mask:0xf\n\t" \
        "v_fmac_f32_dpp %3, %7, %15 row_newbcast:" #N_ " row_mask:0xf bank_mask:0xf\n\t" \
        : "+v"(a0), "+v"(a0b), "+v"(xa0), "+v"(xa0b)                           \
        : "v"(hx), "v"(hy), "v"(hz), "v"(hw),                                  \
          "v"(w0_), "v"(w1_), "v"(w2_), "v"(w3_),                              \
          "v"(x0_), "v"(x1_), "v"(x2_), "v"(x3_))

#define H0A hA0.x,hA0.y,hA0.z,hA0.w
#define H1A hA1.x,hA1.y,hA1.z,hA1.w
#define WV4(C_) wv[4*(C_)], wv[4*(C_)+1], wv[4*(C_)+2], wv[4*(C_)+3]

// Extras panel (verified):
//   group 0 (wave 4):  idx4 = c*32 + l   row = 368+l (l<32), src Wih1
//   group g=1..3 (waves 13..15): idx4 = 800 + (g-1)*1200 + c*48 + l
//                                row = 256 + (g-1)*48 + l (l<48), src Whh1
__global__ void prep_kernel(const float* __restrict__ Wih1,
                            const float* __restrict__ Whh1,
                            float* __restrict__ wsT) {
    int idx = blockIdx.x * 256 + threadIdx.x;     // float index
    if (idx >= NX4 * 4) return;
    int f = idx & 3, q4 = idx >> 2;
    float v;
    if (q4 < 800) {
        int c = q4 / 32, l = q4 % 32;
        v = Wih1[(368 + l) * HH + c * 4 + f];
    } else {
        int r = q4 - 800, grp = r / 1200, rr = r % 1200;
        int c = rr / 48, l = rr % 48;
        v = Whh1[(256 + grp * 48 + l) * HH + c * 4 + f];
    }
    wsT[idx] = v;
}

// Batch-staggered schedule: window w (0..2*NTICK), ONE barrier per window.
//   bx = w&1  : Phase-A batch, tick tA = w>>1  (dots -> gAll[bx], gX[bx])
//   ob = bx^1 : Phase-B batch, tick tB = (w-1)>>1 (cell updates, w>=1)
// Phase B runs before Phase A (inputs ready at barrier). All 100 weight
// floats per thread in registers (wv[100]); only the extras panel streams
// from LDS. Dataflow: B writes shs[.][ob], A reads shs[.][bx], disjoint;
// ybuf write (tick≡1 mod 168) vs read (tick≡167 mod 168) never share a
// window; yacc parities disjoint.
__global__
__attribute__((amdgpu_flat_work_group_size(1024, 1024), amdgpu_waves_per_eu(4, 4)))
void lstm_kernel(const float* __restrict__ X,     // (512,168)
                 const float* __restrict__ Wih0,  // (400,1)
                 const float* __restrict__ Whh0,  // (400,100)
                 const float* __restrict__ bih0,
                 const float* __restrict__ bhh0,
                 const float* __restrict__ Wih1,  // (400,100)
                 const float* __restrict__ Whh1,  // (400,100)
                 const float* __restrict__ bih1,
                 const float* __restrict__ bhh1,
                 const float* __restrict__ fcw,   // (100)
                 const float* __restrict__ fcb,   // (1)
                 const float* __restrict__ wsT,   // extra rows, packed
                 float* __restrict__ out)         // (512,48)
{
    __shared__ __align__(16) float shs[2][2][SHP];   // [layer][batch][k], pad zeros
    __shared__ __align__(16) float4 xlds[NX4P];      // extra-row panel (70.6 KB)
    __shared__ float gAll[2][1024];                  // [batch][unit] partials
    __shared__ float gX[2][NX];                      // [batch] extra-row dots
    __shared__ float sb0[G4], sb1[G4], sw0[G4], sfcw[HH];
    __shared__ float yacc[2], ybuf[2];

    const int t    = threadIdx.x;
    const int lane = t & 63;
    const int wid  = t >> 6;
    const int wg   = blockIdx.x;
    const int b0   = wg * 2;

    // ---- one-time init ----
    for (int i = t; i < 2 * 2 * SHP; i += 1024) ((float*)shs)[i] = 0.0f;
    for (int i = t; i < NX4P; i += 1024)
        xlds[i] = (i < NX4) ? ((const float4*)wsT)[i] : make_float4(0.f, 0.f, 0.f, 0.f);
    if (t < G4) {
        sb0[t] = bih0[t] + bhh0[t];
        sb1[t] = bih1[t] + bhh1[t];
        sw0[t] = Wih0[t];
    }
    if (t < HH) sfcw[t] = fcw[t];
    if (t == 0) { yacc[0] = yacc[1] = 0.0f; ybuf[0] = ybuf[1] = 0.0f; }
    const float fcb0 = fcb[0];

    // ---- register-resident weights: ALL 100 floats (25 float4 chunks) ----
    const float* wrow = (t < 400) ? (Whh0 + t * HH)
                      : (t < 768) ? (Wih1 + (t - 400) * HH)
                                  : (Whh1 + (t - 768) * HH);
    float wv[100];
    #pragma unroll
    for (int j = 0; j < 25; ++j) {
        float4 a = ((const float4*)wrow)[j];
        wv[4*j] = a.x; wv[4*j+1] = a.y; wv[4*j+2] = a.z; wv[4*j+3] = a.w;
    }
    #pragma unroll
    for (int j = 0; j < 100; j += 4)
        asm volatile("" : "+v"(wv[j]), "+v"(wv[j+1]), "+v"(wv[j+2]), "+v"(wv[j+3]));

    // wave-uniform input layer (h0 for waves 0..11, h1 for 12..15)
    const float* hbase = (t < 768) ? &shs[0][0][0] : &shs[1][0][0];

    // h-chunk indices for the replicated DPP layout
    const int r16 = lane & 15;
    const int cL  = r16;                          // chunks 0..15
    const int cH  = 16 + ((r16 < 9) ? r16 : 8);   // chunks 16..24 (clamped)

    // extra-row stream config (wave-uniform)
    const bool xtr   = (wid == 4) || (wid >= 13);
    const int  nact  = (wid == 4) ? 32 : 48;
    const int  xbase = (wid == 4) ? 0 : 800 + (wid - 13) * 1200;
    const int  xu0   = (wid == 4) ? 144 : (wid - 13) * 48;
    const float4* xw = xlds + xbase + lane;          // + c*nact per chunk (LDS)

    // Phase-B task (threads 512..711): task=(t-512); layer=task/100, j=task%100
    const bool pbth = (t >= 512 && t < 712);
    const int  task = t - 512;
    const int  pj   = (task < 100) ? task : task - 100;
    float cA = 0.0f, cB = 0.0f;                      // cell state, batch 0/1
    const float* xrA = X + b0 * LSEQ;
    const float* xrB = X + (b0 + 1) * LSEQ;

    __syncthreads();

    #pragma unroll 1
    for (int w = 0; w <= 2 * NTICK; ++w) {
        const int bx = w & 1;           // Phase-A batch
        const int tA = w >> 1;
        const int ob = bx ^ 1;          // Phase-B batch
        const int tB = (w - 1) >> 1;
        const bool doA = (tA < NTICK);

        // ---- finalize y for previous window's Phase-A batch ----
        if (t == 1023 && w >= 1) {
            const int pbx = (w - 1) & 1, ptA = (w - 1) >> 1;
            if (ptA >= 2 && (ptA - 2) % LSEQ == LSEQ - 1) {
                const int s = (ptA - 2) / LSEQ;
                float y = yacc[pbx] + fcb0;
                ybuf[pbx] = y;
                out[(b0 + pbx) * STEPS + s] = y;
                yacc[pbx] = 0.0f;
            }
        }

        // ===== Phase B FIRST: cell updates for batch ob (inputs ready) =====
        if (w >= 1 && pbth) {
            const int j = pj, b = ob;
            if (task < 100) {                    // L0, global step g0 = tB
                if (tB < 8064) {
                    const int s = tB / LSEQ, p = tB % LSEQ;
                    const float* xr = (b == 0) ? xrA : xrB;
                    float x;
                    if (s == 0)            x = xr[p];
                    else if (p < LSEQ - 1) x = xr[p + 1];
                    else                   x = ybuf[b];
                    float Gi = sb0[j]       + sw0[j]       * x + gAll[b][j];
                    float Gf = sb0[100 + j] + sw0[100 + j] * x + gAll[b][100 + j];
                    float Gg = sb0[200 + j] + sw0[200 + j] * x + gAll[b][200 + j];
                    float Go = sb0[300 + j] + sw0[300 + j] * x + gAll[b][300 + j];
                    float cc = (b == 0) ? cA : cB;
                    cc = sigmoidf_(Gf) * cc + sigmoidf_(Gi) * tanhf_(Gg);
                    shs[0][b][j] = sigmoidf_(Go) * tanhf_(cc);
                    if (b == 0) cA = cc; else cB = cc;
                }
            } else {                             // L1, global step g1 = tB-1
                if (tB >= 1 && tB <= 8064) {
                    // Wih1 row r: r<368 -> gAll[b][400+r], else gX[b][144+(r-368)]
                    // Whh1 row r: r<256 -> gAll[b][768+r], else gX[b][r-256]
                    float Gi = sb1[j]       + gAll[b][400 + j] + gAll[b][768 + j];
                    float Gf = sb1[100 + j] + gAll[b][500 + j] + gAll[b][868 + j];
                    float Gg = sb1[200 + j] + gAll[b][600 + j]
                             + ((j < 56) ? gAll[b][968 + j] : gX[b][j - 56]);
                    float Go = sb1[300 + j]
                             + ((j < 68) ? gAll[b][700 + j] : gX[b][144 + j - 68])
                             + gX[b][44 + j];
                    float cc = (b == 0) ? cA : cB;
                    cc = sigmoidf_(Gf) * cc + sigmoidf_(Gi) * tanhf_(Gg);
                    shs[1][b][j] = sigmoidf_(Go) * tanhf_(cc);
                    if (b == 0) cA = cc; else cB = cc;
                }
            }
        }

        // ================= Phase A: dots for batch bx =================
        if (doA) {
            const float* hsel = hbase + bx * SHP;
            const float4 hA0 = *(const float4*)(hsel + 4 * cL);
            const float4 hA1 = *(const float4*)(hsel + 4 * cH);
            float a0 = 0.f, a0b = 0.f, xa0 = 0.f, xa0b = 0.f;

            if (!xtr) {
                DC10(0,  H0A, WV4(0));
                DC1(1,  H0A, WV4(1));   DC1(2,  H0A, WV4(2));
                DC1(3,  H0A, WV4(3));   DC1(4,  H0A, WV4(4));
                DC1(5,  H0A, WV4(5));   DC1(6,  H0A, WV4(6));
                DC1(7,  H0A, WV4(7));   DC1(8,  H0A, WV4(8));
                DC1(9,  H0A, WV4(9));   DC1(10, H0A, WV4(10));
                DC1(11, H0A, WV4(11));  DC1(12, H0A, WV4(12));
                DC1(13, H0A, WV4(13));  DC1(14, H0A, WV4(14));
                DC1(15, H0A, WV4(15));
                DC1(0,  H1A, WV4(16));  DC1(1,  H1A, WV4(17));
                DC1(2,  H1A, WV4(18));  DC1(3,  H1A, WV4(19));
                DC1(4,  H1A, WV4(20));  DC1(5,  H1A, WV4(21));
                DC1(6,  H1A, WV4(22));  DC1(7,  H1A, WV4(23));
                DC1(8,  H1A, WV4(24));
            } else {
                { const float4 x4 = xw[0*nact];  DC1X0(0,  H0A, WV4(0),  x4.x,x4.y,x4.z,x4.w); }
                { const float4 x4 = xw[1*nact];  DC1X(1,  H0A, WV4(1),  x4.x,x4.y,x4.z,x4.w); }
                { const float4 x4 = xw[2*nact];  DC1X(2,  H0A, WV4(2),  x4.x,x4.y,x4.z,x4.w); }
                { const float4 x4 = xw[3*nact];  DC1X(3,  H0A, WV4(3),  x4.x,x4.y,x4.z,x4.w); }
                { const float4 x4 = xw[4*nact];  DC1X(4,  H0A, WV4(4),  x4.x,x4.y,x4.z,x4.w); }
                { const float4 x4 = xw[5*nact];  DC1X(5,  H0A, WV4(5),  x4.x,x4.y,x4.z,x4.w); }
                { const float4 x4 = xw[6*nact];  DC1X(6,  H0A, WV4(6),  x4.x,x4.y,x4.z,x4.w); }
                { const float4 x4 = xw[7*nact];  DC1X(7,  H0A, WV4(7),  x4.x,x4.y,x4.z,x4.w); }
                { const float4 x4 = xw[8*nact];  DC1X(8,  H0A, WV4(8),  x4.x,x4.y,x4.z,x4.w); }
                { const float4 x4 = xw[9*nact];  DC1X(9,  H0A, WV4(9),  x4.x,x4.y,x4.z,x4.w); }
                { const float4 x4 = xw[10*nact]; DC1X(10, H0A, WV4(10), x4.x,x4.y,x4.z,x4.w); }
                { const float4 x4 = xw[11*nact]; DC1X(11, H0A, WV4(11), x4.x,x4.y,x4.z,x4.w); }
                { const float4 x4 = xw[12*nact]; DC1X(12, H0A, WV4(12), x4.x,x4.y,x4.z,x4.w); }
                { const float4 x4 = xw[13*nact]; DC1X(13, H0A, WV4(13), x4.x,x4.y,x4.z,x4.w); }
                { const float4 x4 = xw[14*nact]; DC1X(14, H0A, WV4(14), x4.x,x4.y,x4.z,x4.w); }
                { const float4 x4 = xw[15*nact]; DC1X(15, H0A, WV4(15), x4.x,x4.y,x4.z,x4.w); }
                { const float4 x4 = xw[16*nact]; DC1X(0,  H1A, WV4(16), x4.x,x4.y,x4.z,x4.w); }
                { const float4 x4 = xw[17*nact]; DC1X(1,  H1A, WV4(17), x4.x,x4.y,x4.z,x4.w); }
                { const float4 x4 = xw[18*nact]; DC1X(2,  H1A, WV4(18), x4.x,x4.y,x4.z,x4.w); }
                { const float4 x4 = xw[19*nact]; DC1X(3,  H1A, WV4(19), x4.x,x4.y,x4.z,x4.w); }
                { const float4 x4 = xw[20*nact]; DC1X(4,  H1A, WV4(20), x4.x,x4.y,x4.z,x4.w); }
                { const float4 x4 = xw[21*nact]; DC1X(5,  H1A, WV4(21), x4.x,x4.y,x4.z,x4.w); }
                { const float4 x4 = xw[22*nact]; DC1X(6,  H1A, WV4(22), x4.x,x4.y,x4.z,x4.w); }
                { const float4 x4 = xw[23*nact]; DC1X(7,  H1A, WV4(23), x4.x,x4.y,x4.z,x4.w); }
                { const float4 x4 = xw[24*nact]; DC1X(8,  H1A, WV4(24), x4.x,x4.y,x4.z,x4.w); }
            }

            gAll[bx][t] = a0 + a0b;
            if (xtr && lane < nact) gX[bx][xu0 + lane] = xa0 + xa0b;

            // y-dot atomics for batch bx (reads shs[1][bx], stable this window)
            if (tA >= 2 && (tA - 2) % LSEQ == LSEQ - 1 && t < 100) {
                atomicAdd(&yacc[bx], sfcw[t] * shs[1][bx][t]);
            }
        }

        __syncthreads();
    }
}

extern "C" void kernel_launch(void* const* d_in, const int* in_sizes, int n_in,
                              void* d_out, int out_size, void* d_ws, size_t ws_size,
                              hipStream_t stream) {
    const float* X    = (const float*)d_in[0];
    const float* Wih0 = (const float*)d_in[1];
    const float* Whh0 = (const float*)d_in[2];
    const float* bih0 = (const float*)d_in[3];
    const float* bhh0 = (const float*)d_in[4];
    const float* Wih1 = (const float*)d_in[5];
    const float* Whh1 = (const float*)d_in[6];
    const float* bih1 = (const float*)d_in[7];
    const float* bhh1 = (const float*)d_in[8];
    const float* fcw  = (const float*)d_in[9];
    const float* fcb  = (const float*)d_in[10];
    float* out = (float*)d_out;
    float* wsT = (float*)d_ws;   // 4400 float4 = 70,400 B

    hipLaunchKernelGGL(prep_kernel, dim3((NX4 * 4 + 255) / 256), dim3(256), 0, stream,
                       Wih1, Whh1, wsT);
    hipLaunchKernelGGL(lstm_kernel, dim3(256), dim3(1024), 0, stream,
                       X, Wih0, Whh0, bih0, bhh0, Wih1, Whh1, bih1, bhh1,
                       fcw, fcb, wsT, out);
}

// Round 17
// 30751.700 us; speedup vs baseline: 1.7264x; 1.7264x over previous
//
#include <hip/hip_runtime.h>

#define HH    100
#define G4    400
#define LSEQ  168
#define STEPS 48
#define NTICK 8066     // per-batch ticks: L0 at tick t (t<8064), L1 at tick t-1
#define SHP   112      // padded h stride (zeros beyond 100)
#define NX    176      // extra rows: Wih1 368..399 (32) + Whh1 256..399 (144)
#define NX4   4400     // float4 units in the extra-row panel
#define NX4P  4416     // padded (waves 13..15 read up to idx 4415)

__device__ __forceinline__ float sigmoidf_(float x) {
    return 1.0f / (1.0f + __expf(-x));
}
__device__ __forceinline__ float tanhf_(float x) {
    return 1.0f - 2.0f / (__expf(2.0f * x) + 1.0f);
}

// ---- DPP broadcast-FMA blocks (single-batch) ------------------------------
// v_fmac_f32_dpp row_newbcast: broadcast within 16-lane rows fused into the
// fmac (~4cy issue; beats readlane 7cy and LDS-broadcast 12cy/b128).
// ROUND-17: restore of the round-13 optimum (30.78 ms). Register budget is
// at its knee: 92 pinned weights + 2 chunks in LDS. wv[100] (r16) spills;
// prefetch queues (r15) add pressure; chain-count (r14) and B-order (r13)
// are neutral. Variadic indirection layer per round-9 lesson. Blocks chain
// through "+v" accumulators -> indivisible (rounds 1-4 spill cascade).

#define DC1(...)   DC1_I(__VA_ARGS__)
#define DC10(...)  DC10_I(__VA_ARGS__)
#define DC1X(...)  DC1X_I(__VA_ARGS__)
#define DC1X0(...) DC1X0_I(__VA_ARGS__)

// One 4-k chunk, 1 batch: 4 DPP-fmacs, chains a0/a0b.
#define DC1_I(N_, hx,hy,hz,hw, w0_,w1_,w2_,w3_)                                \
    asm("v_fmac_f32_dpp %0, %2, %6 row_newbcast:" #N_ " row_mask:0xf bank_mask:0xf\n\t" \
        "v_fmac_f32_dpp %1, %3, %7 row_newbcast:" #N_ " row_mask:0xf bank_mask:0xf\n\t" \
        "v_fmac_f32_dpp %0, %4, %8 row_newbcast:" #N_ " row_mask:0xf bank_mask:0xf\n\t" \
        "v_fmac_f32_dpp %1, %5, %9 row_newbcast:" #N_ " row_mask:0xf bank_mask:0xf\n\t" \
        : "+v"(a0), "+v"(a0b)                                                  \
        : "v"(hx), "v"(hy), "v"(hz), "v"(hw),                                  \
          "v"(w0_), "v"(w1_), "v"(w2_), "v"(w3_))

// First block after the h load: s_nop guards the load->DPP-read window.
#define DC10_I(N_, hx,hy,hz,hw, w0_,w1_,w2_,w3_)                               \
    asm("s_nop 1\n\t"                                                          \
        "v_fmac_f32_dpp %0, %2, %6 row_newbcast:" #N_ " row_mask:0xf bank_mask:0xf\n\t" \
        "v_fmac_f32_dpp %1, %3, %7 row_newbcast:" #N_ " row_mask:0xf bank_mask:0xf\n\t" \
        "v_fmac_f32_dpp %0, %4, %8 row_newbcast:" #N_ " row_mask:0xf bank_mask:0xf\n\t" \
        "v_fmac_f32_dpp %1, %5, %9 row_newbcast:" #N_ " row_mask:0xf bank_mask:0xf\n\t" \
        : "+v"(a0), "+v"(a0b)                                                  \
        : "v"(hx), "v"(hy), "v"(hz), "v"(hw),                                  \
          "v"(w0_), "v"(w1_), "v"(w2_), "v"(w3_))

// Heavy-wave variant: + extras stream. 8 fmacs, 4 chains, distance 4.
#define DC1X_I(N_, hx,hy,hz,hw, w0_,w1_,w2_,w3_, x0_,x1_,x2_,x3_)              \
    asm("v_fmac_f32_dpp %0, %4, %8 row_newbcast:" #N_ " row_mask:0xf bank_mask:0xf\n\t"  \
        "v_fmac_f32_dpp %2, %4, %12 row_newbcast:" #N_ " row_mask:0xf bank_mask:0xf\n\t" \
        "v_fmac_f32_dpp %1, %5, %9 row_newbcast:" #N_ " row_mask:0xf bank_mask:0xf\n\t"  \
        "v_fmac_f32_dpp %3, %5, %13 row_newbcast:" #N_ " row_mask:0xf bank_mask:0xf\n\t" \
        "v_fmac_f32_dpp %0, %6, %10 row_newbcast:" #N_ " row_mask:0xf bank_mask:0xf\n\t" \
        "v_fmac_f32_dpp %2, %6, %14 row_newbcast:" #N_ " row_mask:0xf bank_mask:0xf\n\t" \
        "v_fmac_f32_dpp %1, %7, %11 row_newbcast:" #N_ " row_mask:0xf bank_mask:0xf\n\t" \
        "v_fmac_f32_dpp %3, %7, %15 row_newbcast:" #N_ " row_mask:0xf bank_mask:0xf\n\t" \
        : "+v"(a0), "+v"(a0b), "+v"(xa0), "+v"(xa0b)                           \
        : "v"(hx), "v"(hy), "v"(hz), "v"(hw),                                  \
          "v"(w0_), "v"(w1_), "v"(w2_), "v"(w3_),                              \
          "v"(x0_), "v"(x1_), "v"(x2_), "v"(x3_))

#define DC1X0_I(N_, hx,hy,hz,hw, w0_,w1_,w2_,w3_, x0_,x1_,x2_,x3_)             \
    asm("s_nop 1\n\t"                                                          \
        "v_fmac_f32_dpp %0, %4, %8 row_newbcast:" #N_ " row_mask:0xf bank_mask:0xf\n\t"  \
        "v_fmac_f32_dpp %2, %4, %12 row_newbcast:" #N_ " row_mask:0xf bank_mask:0xf\n\t" \
        "v_fmac_f32_dpp %1, %5, %9 row_newbcast:" #N_ " row_mask:0xf bank_mask:0xf\n\t"  \
        "v_fmac_f32_dpp %3, %5, %13 row_newbcast:" #N_ " row_mask:0xf bank_mask:0xf\n\t" \
        "v_fmac_f32_dpp %0, %6, %10 row_newbcast:" #N_ " row_mask:0xf bank_mask:0xf\n\t" \
        "v_fmac_f32_dpp %2, %6, %14 row_newbcast:" #N_ " row_mask:0xf bank_mask:0xf\n\t" \
        "v_fmac_f32_dpp %1, %7, %11 row_newbcast:" #N_ " row_mask:0xf bank_mask:0xf\n\t" \
        "v_fmac_f32_dpp %3, %7, %15 row_newbcast:" #N_ " row_mask:0xf bank_mask:0xf\n\t" \
        : "+v"(a0), "+v"(a0b), "+v"(xa0), "+v"(xa0b)                           \
        : "v"(hx), "v"(hy), "v"(hz), "v"(hw),                                  \
          "v"(w0_), "v"(w1_), "v"(w2_), "v"(w3_),                              \
          "v"(x0_), "v"(x1_), "v"(x2_), "v"(x3_))

#define H0A hA0.x,hA0.y,hA0.z,hA0.w
#define H1A hA1.x,hA1.y,hA1.z,hA1.w
#define WV4(C_) wv[4*(C_)], wv[4*(C_)+1], wv[4*(C_)+2], wv[4*(C_)+3]

// Extras panel (verified):
//   group 0 (wave 4):  idx4 = c*32 + l   row = 368+l (l<32), src Wih1
//   group g=1..3 (waves 13..15): idx4 = 800 + (g-1)*1200 + c*48 + l
//                                row = 256 + (g-1)*48 + l (l<48), src Whh1
__global__ void prep_kernel(const float* __restrict__ Wih1,
                            const float* __restrict__ Whh1,
                            float* __restrict__ wsT) {
    int idx = blockIdx.x * 256 + threadIdx.x;     // float index
    if (idx >= NX4 * 4) return;
    int f = idx & 3, q4 = idx >> 2;
    float v;
    if (q4 < 800) {
        int c = q4 / 32, l = q4 % 32;
        v = Wih1[(368 + l) * HH + c * 4 + f];
    } else {
        int r = q4 - 800, grp = r / 1200, rr = r % 1200;
        int c = rr / 48, l = rr % 48;
        v = Whh1[(256 + grp * 48 + l) * HH + c * 4 + f];
    }
    wsT[idx] = v;
}

// Batch-staggered schedule: window w (0..2*NTICK), ONE barrier per window.
//   bx = w&1  : Phase-A batch, tick tA = w>>1  (dots -> gAll[bx], gX[bx])
//   ob = bx^1 : Phase-B batch, tick tB = (w-1)>>1 (cell updates, w>=1)
// Phase B runs before Phase A (inputs ready at barrier). Dataflow: B writes
// shs[.][ob], A reads shs[.][bx], disjoint; ybuf write (tick≡1 mod 168) vs
// read (tick≡167 mod 168) never share a window; yacc parities disjoint.
__global__
__attribute__((amdgpu_flat_work_group_size(1024, 1024), amdgpu_waves_per_eu(4, 4)))
void lstm_kernel(const float* __restrict__ X,     // (512,168)
                 const float* __restrict__ Wih0,  // (400,1)
                 const float* __restrict__ Whh0,  // (400,100)
                 const float* __restrict__ bih0,
                 const float* __restrict__ bhh0,
                 const float* __restrict__ Wih1,  // (400,100)
                 const float* __restrict__ Whh1,  // (400,100)
                 const float* __restrict__ bih1,
                 const float* __restrict__ bhh1,
                 const float* __restrict__ fcw,   // (100)
                 const float* __restrict__ fcb,   // (1)
                 const float* __restrict__ wsT,   // extra rows, packed
                 float* __restrict__ out)         // (512,48)
{
    __shared__ __align__(16) float shs[2][2][SHP];   // [layer][batch][k], pad zeros
    __shared__ __align__(16) float4 wlds[2][1024];   // weight chunks 23,24 per unit
    __shared__ __align__(16) float4 xlds[NX4P];      // extra-row panel (70.6 KB)
    __shared__ float gAll[2][1024];                  // [batch][unit] partials
    __shared__ float gX[2][NX];                      // [batch] extra-row dots
    __shared__ float sb0[G4], sb1[G4], sw0[G4], sfcw[HH];
    __shared__ float yacc[2], ybuf[2];

    const int t    = threadIdx.x;
    const int lane = t & 63;
    const int wid  = t >> 6;
    const int wg   = blockIdx.x;
    const int b0   = wg * 2;

    // ---- one-time init ----
    for (int i = t; i < 2 * 2 * SHP; i += 1024) ((float*)shs)[i] = 0.0f;
    for (int i = t; i < NX4P; i += 1024)
        xlds[i] = (i < NX4) ? ((const float4*)wsT)[i] : make_float4(0.f, 0.f, 0.f, 0.f);
    if (t < G4) {
        sb0[t] = bih0[t] + bhh0[t];
        sb1[t] = bih1[t] + bhh1[t];
        sw0[t] = Wih0[t];
    }
    if (t < HH) sfcw[t] = fcw[t];
    if (t == 0) { yacc[0] = yacc[1] = 0.0f; ybuf[0] = ybuf[1] = 0.0f; }
    const float fcb0 = fcb[0];

    // ---- register-resident weights: 92 floats (23 float4 chunks) ----
    const float* wrow = (t < 400) ? (Whh0 + t * HH)
                      : (t < 768) ? (Wih1 + (t - 400) * HH)
                                  : (Whh1 + (t - 768) * HH);
    float wv[92];
    #pragma unroll
    for (int j = 0; j < 23; ++j) {
        float4 a = ((const float4*)wrow)[j];
        wv[4*j] = a.x; wv[4*j+1] = a.y; wv[4*j+2] = a.z; wv[4*j+3] = a.w;
    }
    #pragma unroll
    for (int j = 0; j < 92; j += 4)
        asm volatile("" : "+v"(wv[j]), "+v"(wv[j+1]), "+v"(wv[j+2]), "+v"(wv[j+3]));
    // chunks 23,24 live in LDS
    wlds[0][t] = ((const float4*)wrow)[23];
    wlds[1][t] = ((const float4*)wrow)[24];

    // wave-uniform input layer (h0 for waves 0..11, h1 for 12..15)
    const float* hbase = (t < 768) ? &shs[0][0][0] : &shs[1][0][0];

    // h-chunk indices for the replicated DPP layout
    const int r16 = lane & 15;
    const int cL  = r16;                          // chunks 0..15
    const int cH  = 16 + ((r16 < 9) ? r16 : 8);   // chunks 16..24 (clamped)

    // extra-row stream config (wave-uniform)
    const bool xtr   = (wid == 4) || (wid >= 13);
    const int  nact  = (wid == 4) ? 32 : 48;
    const int  xbase = (wid == 4) ? 0 : 800 + (wid - 13) * 1200;
    const int  xu0   = (wid == 4) ? 144 : (wid - 13) * 48;
    const float4* xw = xlds + xbase + lane;          // + c*nact per chunk (LDS)

    // Phase-B task (threads 512..711): task=(t-512); layer=task/100, j=task%100
    const bool pbth = (t >= 512 && t < 712);
    const int  task = t - 512;
    const int  pj   = (task < 100) ? task : task - 100;
    float cA = 0.0f, cB = 0.0f;                      // cell state, batch 0/1
    const float* xrA = X + b0 * LSEQ;
    const float* xrB = X + (b0 + 1) * LSEQ;

    __syncthreads();

    #pragma unroll 1
    for (int w = 0; w <= 2 * NTICK; ++w) {
        const int bx = w & 1;           // Phase-A batch
        const int tA = w >> 1;
        const int ob = bx ^ 1;          // Phase-B batch
        const int tB = (w - 1) >> 1;
        const bool doA = (tA < NTICK);

        // ---- finalize y for previous window's Phase-A batch ----
        if (t == 1023 && w >= 1) {
            const int pbx = (w - 1) & 1, ptA = (w - 1) >> 1;
            if (ptA >= 2 && (ptA - 2) % LSEQ == LSEQ - 1) {
                const int s = (ptA - 2) / LSEQ;
                float y = yacc[pbx] + fcb0;
                ybuf[pbx] = y;
                out[(b0 + pbx) * STEPS + s] = y;
                yacc[pbx] = 0.0f;
            }
        }

        // ===== Phase B FIRST: cell updates for batch ob (inputs ready) =====
        if (w >= 1 && pbth) {
            const int j = pj, b = ob;
            if (task < 100) {                    // L0, global step g0 = tB
                if (tB < 8064) {
                    const int s = tB / LSEQ, p = tB % LSEQ;
                    const float* xr = (b == 0) ? xrA : xrB;
                    float x;
                    if (s == 0)            x = xr[p];
                    else if (p < LSEQ - 1) x = xr[p + 1];
                    else                   x = ybuf[b];
                    float Gi = sb0[j]       + sw0[j]       * x + gAll[b][j];
                    float Gf = sb0[100 + j] + sw0[100 + j] * x + gAll[b][100 + j];
                    float Gg = sb0[200 + j] + sw0[200 + j] * x + gAll[b][200 + j];
                    float Go = sb0[300 + j] + sw0[300 + j] * x + gAll[b][300 + j];
                    float cc = (b == 0) ? cA : cB;
                    cc = sigmoidf_(Gf) * cc + sigmoidf_(Gi) * tanhf_(Gg);
                    shs[0][b][j] = sigmoidf_(Go) * tanhf_(cc);
                    if (b == 0) cA = cc; else cB = cc;
                }
            } else {                             // L1, global step g1 = tB-1
                if (tB >= 1 && tB <= 8064) {
                    // Wih1 row r: r<368 -> gAll[b][400+r], else gX[b][144+(r-368)]
                    // Whh1 row r: r<256 -> gAll[b][768+r], else gX[b][r-256]
                    float Gi = sb1[j]       + gAll[b][400 + j] + gAll[b][768 + j];
                    float Gf = sb1[100 + j] + gAll[b][500 + j] + gAll[b][868 + j];
                    float Gg = sb1[200 + j] + gAll[b][600 + j]
                             + ((j < 56) ? gAll[b][968 + j] : gX[b][j - 56]);
                    float Go = sb1[300 + j]
                             + ((j < 68) ? gAll[b][700 + j] : gX[b][144 + j - 68])
                             + gX[b][44 + j];
                    float cc = (b == 0) ? cA : cB;
                    cc = sigmoidf_(Gf) * cc + sigmoidf_(Gi) * tanhf_(Gg);
                    shs[1][b][j] = sigmoidf_(Go) * tanhf_(cc);
                    if (b == 0) cA = cc; else cB = cc;
                }
            }
        }

        // ================= Phase A: dots for batch bx =================
        if (doA) {
            const float* hsel = hbase + bx * SHP;
            const float4 hA0 = *(const float4*)(hsel + 4 * cL);
            const float4 hA1 = *(const float4*)(hsel + 4 * cH);
            float a0 = 0.f, a0b = 0.f, xa0 = 0.f, xa0b = 0.f;

            if (!xtr) {
                DC10(0,  H0A, WV4(0));
                DC1(1,  H0A, WV4(1));   DC1(2,  H0A, WV4(2));
                DC1(3,  H0A, WV4(3));   DC1(4,  H0A, WV4(4));
                DC1(5,  H0A, WV4(5));   DC1(6,  H0A, WV4(6));
                DC1(7,  H0A, WV4(7));   DC1(8,  H0A, WV4(8));
                DC1(9,  H0A, WV4(9));   DC1(10, H0A, WV4(10));
                DC1(11, H0A, WV4(11));  DC1(12, H0A, WV4(12));
                DC1(13, H0A, WV4(13));  DC1(14, H0A, WV4(14));
                DC1(15, H0A, WV4(15));
                DC1(0,  H1A, WV4(16));  DC1(1,  H1A, WV4(17));
                DC1(2,  H1A, WV4(18));  DC1(3,  H1A, WV4(19));
                DC1(4,  H1A, WV4(20));  DC1(5,  H1A, WV4(21));
                DC1(6,  H1A, WV4(22));
                { const float4 wl = wlds[0][t]; DC1(7, H1A, wl.x, wl.y, wl.z, wl.w); }
                { const float4 wl = wlds[1][t]; DC1(8, H1A, wl.x, wl.y, wl.z, wl.w); }
            } else {
                { const float4 x4 = xw[0*nact];  DC1X0(0,  H0A, WV4(0),  x4.x,x4.y,x4.z,x4.w); }
                { const float4 x4 = xw[1*nact];  DC1X(1,  H0A, WV4(1),  x4.x,x4.y,x4.z,x4.w); }
                { const float4 x4 = xw[2*nact];  DC1X(2,  H0A, WV4(2),  x4.x,x4.y,x4.z,x4.w); }
                { const float4 x4 = xw[3*nact];  DC1X(3,  H0A, WV4(3),  x4.x,x4.y,x4.z,x4.w); }
                { const float4 x4 = xw[4*nact];  DC1X(4,  H0A, WV4(4),  x4.x,x4.y,x4.z,x4.w); }
                { const float4 x4 = xw[5*nact];  DC1X(5,  H0A, WV4(5),  x4.x,x4.y,x4.z,x4.w); }
                { const float4 x4 = xw[6*nact];  DC1X(6,  H0A, WV4(6),  x4.x,x4.y,x4.z,x4.w); }
                { const float4 x4 = xw[7*nact];  DC1X(7,  H0A, WV4(7),  x4.x,x4.y,x4.z,x4.w); }
                { const float4 x4 = xw[8*nact];  DC1X(8,  H0A, WV4(8),  x4.x,x4.y,x4.z,x4.w); }
                { const float4 x4 = xw[9*nact];  DC1X(9,  H0A, WV4(9),  x4.x,x4.y,x4.z,x4.w); }
                { const float4 x4 = xw[10*nact]; DC1X(10, H0A, WV4(10), x4.x,x4.y,x4.z,x4.w); }
                { const float4 x4 = xw[11*nact]; DC1X(11, H0A, WV4(11), x4.x,x4.y,x4.z,x4.w); }
                { const float4 x4 = xw[12*nact]; DC1X(12, H0A, WV4(12), x4.x,x4.y,x4.z,x4.w); }
                { const float4 x4 = xw[13*nact]; DC1X(13, H0A, WV4(13), x4.x,x4.y,x4.z,x4.w); }
                { const float4 x4 = xw[14*nact]; DC1X(14, H0A, WV4(14), x4.x,x4.y,x4.z,x4.w); }
                { const float4 x4 = xw[15*nact]; DC1X(15, H0A, WV4(15), x4.x,x4.y,x4.z,x4.w); }
                { const float4 x4 = xw[16*nact]; DC1X(0,  H1A, WV4(16), x4.x,x4.y,x4.z,x4.w); }
                { const float4 x4 = xw[17*nact]; DC1X(1,  H1A, WV4(17), x4.x,x4.y,x4.z,x4.w); }
                { const float4 x4 = xw[18*nact]; DC1X(2,  H1A, WV4(18), x4.x,x4.y,x4.z,x4.w); }
                { const float4 x4 = xw[19*nact]; DC1X(3,  H1A, WV4(19), x4.x,x4.y,x4.z,x4.w); }
                { const float4 x4 = xw[20*nact]; DC1X(4,  H1A, WV4(20), x4.x,x4.y,x4.z,x4.w); }
                { const float4 x4 = xw[21*nact]; DC1X(5,  H1A, WV4(21), x4.x,x4.y,x4.z,x4.w); }
                { const float4 x4 = xw[22*nact]; DC1X(6,  H1A, WV4(22), x4.x,x4.y,x4.z,x4.w); }
                { const float4 x4 = xw[23*nact]; const float4 wl = wlds[0][t];
                  DC1X(7, H1A, wl.x, wl.y, wl.z, wl.w, x4.x, x4.y, x4.z, x4.w); }
                { const float4 x4 = xw[24*nact]; const float4 wl = wlds[1][t];
                  DC1X(8, H1A, wl.x, wl.y, wl.z, wl.w, x4.x, x4.y, x4.z, x4.w); }
            }

            gAll[bx][t] = a0 + a0b;
            if (xtr && lane < nact) gX[bx][xu0 + lane] = xa0 + xa0b;

            // y-dot atomics for batch bx (reads shs[1][bx], stable this window)
            if (tA >= 2 && (tA - 2) % LSEQ == LSEQ - 1 && t < 100) {
                atomicAdd(&yacc[bx], sfcw[t] * shs[1][bx][t]);
            }
        }

        __syncthreads();
    }
}

extern "C" void kernel_launch(void* const* d_in, const int* in_sizes, int n_in,
                              void* d_out, int out_size, void* d_ws, size_t ws_size,
                              hipStream_t stream) {
    const float* X    = (const float*)d_in[0];
    const float* Wih0 = (const float*)d_in[1];
    const float* Whh0 = (const float*)d_in[2];
    const float* bih0 = (const float*)d_in[3];
    const float* bhh0 = (const float*)d_in[4];
    const float* Wih1 = (const float*)d_in[5];
    const float* Whh1 = (const float*)d_in[6];
    const float* bih1 = (const float*)d_in[7];
    const float* bhh1 = (const float*)d_in[8];
    const float* fcw  = (const float*)d_in[9];
    const float* fcb  = (const float*)d_in[10];
    float* out = (float*)d_out;
    float* wsT = (float*)d_ws;   // 4400 float4 = 70,400 B

    hipLaunchKernelGGL(prep_kernel, dim3((NX4 * 4 + 255) / 256), dim3(256), 0, stream,
                       Wih1, Whh1, wsT);
    hipLaunchKernelGGL(lstm_kernel, dim3(256), dim3(1024), 0, stream,
                       X, Wih0, Whh0, bih0, bhh0, Wih1, Whh1, bih1, bhh1,
                       fcw, fcb, wsT, out);
}